// Round 10
// baseline (1681.776 us; speedup 1.0000x reference)
//
#include <hip/hip_runtime.h>

typedef __attribute__((ext_vector_type(8))) short short8;
typedef __attribute__((ext_vector_type(4))) float f32x4;
typedef __attribute__((ext_vector_type(4))) uint  uintx4;

#define RTOL_K 3e-4f
#define ATOL_K 3e-5f

__device__ __forceinline__ ushort f2bf(float f) {
    union { float f; uint u; } v; v.f = f;
    uint r = v.u + 0x7fffu + ((v.u >> 16) & 1u);   // RNE
    return (ushort)(r >> 16);
}

// packed f32->bf16 (RNE), D.lo = cvt(a), D.hi = cvt(b)
__device__ __forceinline__ uint cvt_pk_bf16(float a, float b) {
    uint r;
    asm("v_cvt_pk_bf16_f32 %0, %1, %2" : "=v"(r) : "v"(a), "v"(b));
    return r;
}

// ws layout (bytes): W1f 0K | W2f 4K | W3f 12K | b1f 14K | b2f 18K | counter 22K
#define WS_W1F 0
#define WS_W2F 4096
#define WS_W3F 12288
#define WS_B1F 14336
#define WS_B2F 18432
#define WS_CNT 22528

// Assumed A/B fragment k-map: k=(lane>>4)*8+j, m/n=lane&15 — used consistently
// on build and dynamic packing so any k-permutation cancels in the MFMA sum.
__global__ __launch_bounds__(64) void build_frags(
    const float* __restrict__ W1, const float* __restrict__ b1,
    const float* __restrict__ W2, const float* __restrict__ b2,
    const float* __restrict__ W3, const float* __restrict__ b3,
    char* __restrict__ ws)
{
    int lane = threadIdx.x;
    int m = lane & 15, g = lane >> 4;
    ushort* w1f = (ushort*)(ws + WS_W1F);
    ushort* w2f = (ushort*)(ws + WS_W2F);
    ushort* w3f = (ushort*)(ws + WS_W3F);
    float*  b1f = (float*)(ws + WS_B1F);
    float*  b2f = (float*)(ws + WS_B2F);
    for (int mt = 0; mt < 4; ++mt)
        for (int j = 0; j < 8; ++j) {
            int k = g * 8 + j;
            w1f[(mt*64 + lane)*8 + j] = (k < 4) ? f2bf(W1[(16*mt + m)*4 + k]) : (ushort)0;
        }
    for (int kt = 0; kt < 2; ++kt)
        for (int mt = 0; mt < 4; ++mt)
            for (int j = 0; j < 8; ++j) {
                int k = 32*kt + g*8 + j;
                w2f[((kt*4 + mt)*64 + lane)*8 + j] = f2bf(W2[(16*mt + m)*64 + k]);
            }
    for (int kt = 0; kt < 2; ++kt)
        for (int j = 0; j < 8; ++j) {
            int k = 32*kt + g*8 + j;
            w3f[(kt*64 + lane)*8 + j] = (m < 3) ? f2bf(W3[m*64 + k]) : (ushort)0;
        }
    for (int mt = 0; mt < 4; ++mt)
        for (int r = 0; r < 4; ++r) {           // verified C/D layout: row=(l>>4)*4+r
            b1f[(mt*64 + lane)*4 + r] = b1[16*mt + g*4 + r];
            b2f[(mt*64 + lane)*4 + r] = b2[16*mt + g*4 + r];
        }
}

// ---------- per-cohort state / controller macros (static names, rule #20) ----------
#define K_STATE(X) \
    float k##X##00=0,k##X##01=0,k##X##02=0, k##X##10=0,k##X##11=0,k##X##12=0, \
          k##X##20=0,k##X##21=0,k##X##22=0, k##X##30=0,k##X##31=0,k##X##32=0, \
          k##X##40=0,k##X##41=0,k##X##42=0, k##X##50=0,k##X##51=0,k##X##52=0, \
          k##X##60=0,k##X##61=0,k##X##62=0;

#define REFILL(X) \
    if (!active##X && !drained) { \
        int i_ = atomicAdd(counter, 1); \
        if (i_ < n) { \
            idx##X = i_; \
            float4 e_ = reinterpret_cast<const float4*>(ev)[i_]; \
            y##X##0 = e_.x; y##X##1 = e_.y; y##X##2 = e_.z; pol##X = e_.w; \
            t##X = 0.f; dt##X = 0.05f; iters##X = 0; active##X = true; \
        } else drained = true; \
    }

#define STAGE_IN(X) \
    float yi##X##0 = y##X##0, yi##X##1 = y##X##1, yi##X##2 = y##X##2, cs##X = 0.0f; \
    switch (s) { \
    case 0: break; \
    case 1: cs##X = 0.2f; \
        yi##X##0 = fmaf(dte##X, a21*k##X##00, y##X##0); \
        yi##X##1 = fmaf(dte##X, a21*k##X##01, y##X##1); \
        yi##X##2 = fmaf(dte##X, a21*k##X##02, y##X##2); \
        break; \
    case 2: cs##X = 0.3f; \
        yi##X##0 = fmaf(dte##X, fmaf(a32c,k##X##10, a31*k##X##00), y##X##0); \
        yi##X##1 = fmaf(dte##X, fmaf(a32c,k##X##11, a31*k##X##01), y##X##1); \
        yi##X##2 = fmaf(dte##X, fmaf(a32c,k##X##12, a31*k##X##02), y##X##2); \
        break; \
    case 3: cs##X = 0.8f; \
        yi##X##0 = fmaf(dte##X, fmaf(a43,k##X##20, fmaf(a42,k##X##10, a41*k##X##00)), y##X##0); \
        yi##X##1 = fmaf(dte##X, fmaf(a43,k##X##21, fmaf(a42,k##X##11, a41*k##X##01)), y##X##1); \
        yi##X##2 = fmaf(dte##X, fmaf(a43,k##X##22, fmaf(a42,k##X##12, a41*k##X##02)), y##X##2); \
        break; \
    case 4: cs##X = 8.f/9.f; \
        yi##X##0 = fmaf(dte##X, fmaf(a54,k##X##30, fmaf(a53,k##X##20, fmaf(a52,k##X##10, a51*k##X##00))), y##X##0); \
        yi##X##1 = fmaf(dte##X, fmaf(a54,k##X##31, fmaf(a53,k##X##21, fmaf(a52,k##X##11, a51*k##X##01))), y##X##1); \
        yi##X##2 = fmaf(dte##X, fmaf(a54,k##X##32, fmaf(a53,k##X##22, fmaf(a52,k##X##12, a51*k##X##02))), y##X##2); \
        break; \
    case 5: cs##X = 1.0f; \
        yi##X##0 = fmaf(dte##X, fmaf(a65,k##X##40, fmaf(a64,k##X##30, fmaf(a63,k##X##20, fmaf(a62,k##X##10, a61*k##X##00)))), y##X##0); \
        yi##X##1 = fmaf(dte##X, fmaf(a65,k##X##41, fmaf(a64,k##X##31, fmaf(a63,k##X##21, fmaf(a62,k##X##11, a61*k##X##01)))), y##X##1); \
        yi##X##2 = fmaf(dte##X, fmaf(a65,k##X##42, fmaf(a64,k##X##32, fmaf(a63,k##X##22, fmaf(a62,k##X##12, a61*k##X##02)))), y##X##2); \
        break; \
    case 6: cs##X = 1.0f; \
        yi##X##0 = fmaf(dte##X, fmaf(a76,k##X##50, fmaf(a75,k##X##40, fmaf(a74,k##X##30, fmaf(a73,k##X##20, a71*k##X##00)))), y##X##0); \
        yi##X##1 = fmaf(dte##X, fmaf(a76,k##X##51, fmaf(a75,k##X##41, fmaf(a74,k##X##31, fmaf(a73,k##X##21, a71*k##X##01)))), y##X##1); \
        yi##X##2 = fmaf(dte##X, fmaf(a76,k##X##52, fmaf(a75,k##X##42, fmaf(a74,k##X##32, fmaf(a73,k##X##22, a71*k##X##02)))), y##X##2); \
        y5##X##0 = yi##X##0; y5##X##1 = yi##X##1; y5##X##2 = yi##X##2;  /* FSAL */ \
        break; \
    }

#define STAGE_OUT(X) \
    switch (s) { \
    case 0: k##X##00=r##X##0; k##X##01=r##X##1; k##X##02=r##X##2; break; \
    case 1: k##X##10=r##X##0; k##X##11=r##X##1; k##X##12=r##X##2; break; \
    case 2: k##X##20=r##X##0; k##X##21=r##X##1; k##X##22=r##X##2; break; \
    case 3: k##X##30=r##X##0; k##X##31=r##X##1; k##X##32=r##X##2; break; \
    case 4: k##X##40=r##X##0; k##X##41=r##X##1; k##X##42=r##X##2; break; \
    case 5: k##X##50=r##X##0; k##X##51=r##X##1; k##X##52=r##X##2; break; \
    case 6: k##X##60=r##X##0; k##X##61=r##X##1; k##X##62=r##X##2; break; \
    }

#define EPILOGUE(X) \
    if (active##X) { \
        float er0 = dte##X * fmaf(e7,k##X##60, fmaf(e6,k##X##50, fmaf(e5,k##X##40, fmaf(e4,k##X##30, fmaf(e3,k##X##20, e1*k##X##00))))); \
        float er1 = dte##X * fmaf(e7,k##X##61, fmaf(e6,k##X##51, fmaf(e5,k##X##41, fmaf(e4,k##X##31, fmaf(e3,k##X##21, e1*k##X##01))))); \
        float er2 = dte##X * fmaf(e7,k##X##62, fmaf(e6,k##X##52, fmaf(e5,k##X##42, fmaf(e4,k##X##32, fmaf(e3,k##X##22, e1*k##X##02))))); \
        float sc0 = fmaf(RTOL_K, fmaxf(fabsf(y##X##0), fabsf(y5##X##0)), ATOL_K); \
        float sc1 = fmaf(RTOL_K, fmaxf(fabsf(y##X##1), fabsf(y5##X##1)), ATOL_K); \
        float sc2 = fmaf(RTOL_K, fmaxf(fabsf(y##X##2), fabsf(y5##X##2)), ATOL_K); \
        float q0 = er0/sc0, q1 = er1/sc1, q2 = er2/sc2; \
        float en = sqrtf((q0*q0 + q1*q1 + q2*q2) * (1.0f/3.0f)); \
        en = fmaxf(en, 1e-10f); \
        if (en <= 1.0f) { t##X += dte##X; y##X##0 = y5##X##0; y##X##1 = y5##X##1; y##X##2 = y5##X##2; } \
        float fac = fminf(fmaxf(0.9f * exp2f(-0.2f * log2f(en)), 0.2f), 10.0f); \
        dt##X = dte##X * fac; \
        ++iters##X; \
        if (t##X >= 1.0f - 1e-9f || iters##X >= 64) { \
            reinterpret_cast<float4*>(out)[idx##X] = make_float4(y##X##0, y##X##1, y##X##2, pol##X); \
            active##X = false; \
        } \
    }

// ---------- dual stage_eval building blocks (OFF = cohort LDS byte offset) ----------
#define L1_BLOCK(X) \
    uint bp##X##01 = (uint)__builtin_amdgcn_ds_bpermute(xaddr[nt], (int)px##X##01); \
    uint bp##X##23 = (uint)__builtin_amdgcn_ds_bpermute(xaddr[nt], (int)px##X##23); \
    uintx4 bxw##X = { g0 ? bp##X##01 : 0u, g0 ? bp##X##23 : 0u, 0u, 0u }; \
    short8 bx##X = __builtin_bit_cast(short8, bxw##X); \
    f32x4 a##X##0 = __builtin_amdgcn_mfma_f32_16x16x32_bf16(W1r[0], bx##X, b1r[0], 0, 0, 0); \
    f32x4 a##X##1 = __builtin_amdgcn_mfma_f32_16x16x32_bf16(W1r[1], bx##X, b1r[1], 0, 0, 0); \
    f32x4 a##X##2 = __builtin_amdgcn_mfma_f32_16x16x32_bf16(W1r[2], bx##X, b1r[2], 0, 0, 0); \
    f32x4 a##X##3 = __builtin_amdgcn_mfma_f32_16x16x32_bf16(W1r[3], bx##X, b1r[3], 0, 0, 0);

#define PACK_STORE(V0, V1, V2, V3, OFF) \
    { uint q0_ = cvt_pk_bf16(fmaxf(V0[0],0.f), fmaxf(V0[1],0.f)); \
      uint q1_ = cvt_pk_bf16(fmaxf(V0[2],0.f), fmaxf(V0[3],0.f)); \
      *(uint2*)(hwp[0] + 2048*nt + (OFF)) = make_uint2(q0_, q1_); \
      q0_ = cvt_pk_bf16(fmaxf(V1[0],0.f), fmaxf(V1[1],0.f)); \
      q1_ = cvt_pk_bf16(fmaxf(V1[2],0.f), fmaxf(V1[3],0.f)); \
      *(uint2*)(hwp[1] + 2048*nt + (OFF)) = make_uint2(q0_, q1_); \
      q0_ = cvt_pk_bf16(fmaxf(V2[0],0.f), fmaxf(V2[1],0.f)); \
      q1_ = cvt_pk_bf16(fmaxf(V2[2],0.f), fmaxf(V2[3],0.f)); \
      *(uint2*)(hwp[2] + 2048*nt + (OFF)) = make_uint2(q0_, q1_); \
      q0_ = cvt_pk_bf16(fmaxf(V3[0],0.f), fmaxf(V3[1],0.f)); \
      q1_ = cvt_pk_bf16(fmaxf(V3[2],0.f), fmaxf(V3[3],0.f)); \
      *(uint2*)(hwp[3] + 2048*nt + (OFF)) = make_uint2(q0_, q1_); }

#define L2_BLOCK(X, OFF) \
    short8 bh##X##0 = *(const short8*)(hrp[0] + 2048*nt + (OFF)); \
    short8 bh##X##1 = *(const short8*)(hrp[1] + 2048*nt + (OFF)); \
    f32x4 c##X##0 = __builtin_amdgcn_mfma_f32_16x16x32_bf16(W2r[0][0], bh##X##0, b2r[0], 0, 0, 0); \
    f32x4 c##X##1 = __builtin_amdgcn_mfma_f32_16x16x32_bf16(W2r[0][1], bh##X##0, b2r[1], 0, 0, 0); \
    f32x4 c##X##2 = __builtin_amdgcn_mfma_f32_16x16x32_bf16(W2r[0][2], bh##X##0, b2r[2], 0, 0, 0); \
    f32x4 c##X##3 = __builtin_amdgcn_mfma_f32_16x16x32_bf16(W2r[0][3], bh##X##0, b2r[3], 0, 0, 0); \
    c##X##0 = __builtin_amdgcn_mfma_f32_16x16x32_bf16(W2r[1][0], bh##X##1, c##X##0, 0, 0, 0); \
    c##X##1 = __builtin_amdgcn_mfma_f32_16x16x32_bf16(W2r[1][1], bh##X##1, c##X##1, 0, 0, 0); \
    c##X##2 = __builtin_amdgcn_mfma_f32_16x16x32_bf16(W2r[1][2], bh##X##1, c##X##2, 0, 0, 0); \
    c##X##3 = __builtin_amdgcn_mfma_f32_16x16x32_bf16(W2r[1][3], bh##X##1, c##X##3, 0, 0, 0);

#define L3_BLOCK(X, OFF, KOFF) \
    short8 d##X##0 = *(const short8*)(hrp[0] + 2048*nt + (OFF)); \
    short8 d##X##1 = *(const short8*)(hrp[1] + 2048*nt + (OFF)); \
    f32x4 k3##X = __builtin_amdgcn_mfma_f32_16x16x32_bf16(W3r[0], d##X##0, zero4, 0, 0, 0); \
    k3##X = __builtin_amdgcn_mfma_f32_16x16x32_bf16(W3r[1], d##X##1, k3##X, 0, 0, 0); \
    if (g0) *(f32x4*)(kwp + 256*nt + (KOFF)) = k3##X;

// LDS: HsA [0,8K) | HsB [8K,16K) | KsA [16K,17K) | KsB [17K,18K)  = 18432 B
// -> 8 blocks/CU (matches the 2-wave/SIMD VGPR tier). Grid 2048 = 8/CU.
__global__ __launch_bounds__(64) void node_warp_kernel(
    const float* __restrict__ ev, const char* __restrict__ ws,
    const float* __restrict__ b3g,
    float* __restrict__ out, int n, int* __restrict__ counter)
{
    __shared__ __align__(128) char smem[18432];

    const int lane = threadIdx.x;
    const int g = lane >> 4, m = lane & 15;
    const bool g0 = (g == 0);

    const short8* W1f = (const short8*)(ws + WS_W1F);
    const short8* W2f = (const short8*)(ws + WS_W2F);
    const short8* W3f = (const short8*)(ws + WS_W3F);
    const f32x4*  b1f = (const f32x4*)(ws + WS_B1F);
    const f32x4*  b2f = (const f32x4*)(ws + WS_B2F);
    short8 W1r[4], W2r[2][4], W3r[2];
    f32x4  b1r[4], b2r[4];
#pragma unroll
    for (int mt = 0; mt < 4; ++mt) {
        W1r[mt] = W1f[mt*64 + lane];
        W2r[0][mt] = W2f[(0*4 + mt)*64 + lane];
        W2r[1][mt] = W2f[(1*4 + mt)*64 + lane];
        b1r[mt] = b1f[mt*64 + lane];
        b2r[mt] = b2f[mt*64 + lane];
    }
    W3r[0] = W3f[0*64 + lane];
    W3r[1] = W3f[1*64 + lane];
    const float b30 = b3g[0], b31 = b3g[1], b32 = b3g[2];
    const f32x4 zero4 = {0.f, 0.f, 0.f, 0.f};

    // per-lane LDS pointers (cohort A base; B = +8192 / +1024 immediates)
    const uint hswz = (uint)((m & 7) << 4);
    char* hwp[4];
#pragma unroll
    for (int mt = 0; mt < 4; ++mt)
        hwp[mt] = smem + 128*m + ((uint)(32*mt + 8*g) ^ hswz);
    char* hrp[2];
#pragma unroll
    for (int kt = 0; kt < 2; ++kt)
        hrp[kt] = smem + 128*m + ((uint)(16*g + 64*kt) ^ hswz);
    char* kwp = smem + 16384 + m * 16;
    const char* krp = smem + 16384 + lane * 16;
    int xaddr[4];
#pragma unroll
    for (int nt = 0; nt < 4; ++nt) xaddr[nt] = (16*nt + m) * 4;

    // DOPRI5 tableau
    constexpr float a21 = 1.f/5.f;
    constexpr float a31 = 3.f/40.f,  a32c = 9.f/40.f;
    constexpr float a41 = 44.f/45.f, a42 = -56.f/15.f, a43 = 32.f/9.f;
    constexpr float a51 = 19372.f/6561.f, a52 = -25360.f/2187.f,
                    a53 = 64448.f/6561.f, a54 = -212.f/729.f;
    constexpr float a61 = 9017.f/3168.f,  a62 = -355.f/33.f,
                    a63 = 46732.f/5247.f, a64 = 49.f/176.f, a65 = -5103.f/18656.f;
    constexpr float a71 = 35.f/384.f, a73 = 500.f/1113.f, a74 = 125.f/192.f,
                    a75 = -2187.f/6784.f, a76 = 11.f/84.f;
    constexpr float e1 = (float)(35.0/384.0   - 5179.0/57600.0);
    constexpr float e3 = (float)(500.0/1113.0 - 7571.0/16695.0);
    constexpr float e4 = (float)(125.0/192.0  - 393.0/640.0);
    constexpr float e5 = (float)(-2187.0/6784.0 + 92097.0/339200.0);
    constexpr float e6 = (float)(11.0/84.0    - 187.0/2100.0);
    constexpr float e7 = (float)(-1.0/40.0);

    bool drained = false;
    bool activeA = false, activeB = false;
    int  idxA = -1, idxB = -1, itersA = 0, itersB = 0;
    float tA = 0.f, dtA = 0.05f, yA0 = 0.f, yA1 = 0.f, yA2 = 0.f, polA = 0.f;
    float tB = 0.f, dtB = 0.05f, yB0 = 0.f, yB1 = 0.f, yB2 = 0.f, polB = 0.f;
    K_STATE(A)
    K_STATE(B)

    for (;;) {
        REFILL(A)
        REFILL(B)
        if (__all(!activeA) && __all(!activeB)) break;

        float dteA = fminf(dtA, 1.0f - tA);
        float dteB = fminf(dtB, 1.0f - tB);
        float y5A0 = yA0, y5A1 = yA1, y5A2 = yA2;
        float y5B0 = yB0, y5B1 = yB1, y5B2 = yB2;

        // stage evals are UNPREDICATED (MFMA needs all 64 lanes); A and B are
        // independent streams -> layer-level interleave fills each other's
        // bpermute/ds_read/MFMA latency within the single resident wave pair.
#pragma unroll 1
        for (int s = 0; s < 7; ++s) {
            STAGE_IN(A)
            STAGE_IN(B)
            float tsA = fmaf(csA, dteA, tA);
            float tsB = fmaf(csB, dteB, tB);
            uint pxA01 = cvt_pk_bf16(yiA0, yiA1), pxA23 = cvt_pk_bf16(yiA2, tsA);
            uint pxB01 = cvt_pk_bf16(yiB0, yiB1), pxB23 = cvt_pk_bf16(yiB2, tsB);
#pragma unroll
            for (int nt = 0; nt < 4; ++nt) {
                L1_BLOCK(A)
                L1_BLOCK(B)
                PACK_STORE(aA0, aA1, aA2, aA3, 0)
                PACK_STORE(aB0, aB1, aB2, aB3, 8192)
                L2_BLOCK(A, 0)
                L2_BLOCK(B, 8192)
                PACK_STORE(cA0, cA1, cA2, cA3, 0)
                PACK_STORE(cB0, cB1, cB2, cB3, 8192)
                L3_BLOCK(A, 0, 0)
                L3_BLOCK(B, 8192, 1024)
            }
            f32x4 kvA = *(const f32x4*)krp;
            f32x4 kvB = *(const f32x4*)(krp + 1024);
            float rA0 = kvA[0] + b30, rA1 = kvA[1] + b31, rA2 = kvA[2] + b32;
            float rB0 = kvB[0] + b30, rB1 = kvB[1] + b31, rB2 = kvB[2] + b32;
            STAGE_OUT(A)
            STAGE_OUT(B)
        }

        EPILOGUE(A)
        EPILOGUE(B)
    }
}

extern "C" void kernel_launch(void* const* d_in, const int* in_sizes, int n_in,
                              void* d_out, int out_size, void* d_ws, size_t ws_size,
                              hipStream_t stream)
{
    const float* events = (const float*)d_in[0];
    const float* W1 = (const float*)d_in[1];
    const float* b1 = (const float*)d_in[2];
    const float* W2 = (const float*)d_in[3];
    const float* b2 = (const float*)d_in[4];
    const float* W3 = (const float*)d_in[5];
    const float* b3 = (const float*)d_in[6];
    float* out = (float*)d_out;

    char* ws = (char*)d_ws;
    int* counter = (int*)(ws + WS_CNT);
    int n = in_sizes[0] / 4;

    hipMemsetAsync(counter, 0, sizeof(int), stream);
    hipLaunchKernelGGL(build_frags, dim3(1), dim3(64), 0, stream,
                       W1, b1, W2, b2, W3, b3, ws);

    // 8 blocks/CU (LDS 18.4KB cap) x 1 wave, each wave runs TWO event cohorts.
    const int grid = 2048;
    hipLaunchKernelGGL(node_warp_kernel, dim3(grid), dim3(64), 0, stream,
                       events, ws, b3, out, n, counter);
}

// Round 12
// 1525.407 us; speedup vs baseline: 1.1025x; 1.1025x over previous
//
#include <hip/hip_runtime.h>

typedef __attribute__((ext_vector_type(8))) short short8;
typedef __attribute__((ext_vector_type(4))) float f32x4;
typedef __attribute__((ext_vector_type(4))) uint  uintx4;

#define RTOL_K 3e-4f
#define ATOL_K 3e-5f

__device__ __forceinline__ ushort f2bf(float f) {
    union { float f; uint u; } v; v.f = f;
    uint r = v.u + 0x7fffu + ((v.u >> 16) & 1u);   // RNE
    return (ushort)(r >> 16);
}

// packed f32->bf16 (RNE), D.lo = cvt(a), D.hi = cvt(b)
__device__ __forceinline__ uint cvt_pk_bf16(float a, float b) {
    uint r;
    asm("v_cvt_pk_bf16_f32 %0, %1, %2" : "=v"(r) : "v"(a), "v"(b));
    return r;
}

// ws layout (bytes): W1f 0K | W2f 4K | W3f 12K | b1f 14K | b2f 18K | counter 22K
#define WS_W1F 0
#define WS_W2F 4096
#define WS_W3F 12288
#define WS_B1F 14336
#define WS_B2F 18432
#define WS_CNT 22528

// Assumed A/B fragment k-map: k=(lane>>4)*8+j, m/n=lane&15 — used consistently
// on build and dynamic packing so any k-permutation cancels in the MFMA sum.
__global__ __launch_bounds__(64) void build_frags(
    const float* __restrict__ W1, const float* __restrict__ b1,
    const float* __restrict__ W2, const float* __restrict__ b2,
    const float* __restrict__ W3, const float* __restrict__ b3,
    char* __restrict__ ws)
{
    int lane = threadIdx.x;
    int m = lane & 15, g = lane >> 4;
    ushort* w1f = (ushort*)(ws + WS_W1F);
    ushort* w2f = (ushort*)(ws + WS_W2F);
    ushort* w3f = (ushort*)(ws + WS_W3F);
    float*  b1f = (float*)(ws + WS_B1F);
    float*  b2f = (float*)(ws + WS_B2F);
    for (int mt = 0; mt < 4; ++mt)
        for (int j = 0; j < 8; ++j) {
            int k = g * 8 + j;
            w1f[(mt*64 + lane)*8 + j] = (k < 4) ? f2bf(W1[(16*mt + m)*4 + k]) : (ushort)0;
        }
    for (int kt = 0; kt < 2; ++kt)
        for (int mt = 0; mt < 4; ++mt)
            for (int j = 0; j < 8; ++j) {
                int k = 32*kt + g*8 + j;
                w2f[((kt*4 + mt)*64 + lane)*8 + j] = f2bf(W2[(16*mt + m)*64 + k]);
            }
    for (int kt = 0; kt < 2; ++kt)
        for (int j = 0; j < 8; ++j) {
            int k = 32*kt + g*8 + j;
            w3f[(kt*64 + lane)*8 + j] = (m < 3) ? f2bf(W3[m*64 + k]) : (ushort)0;
        }
    for (int mt = 0; mt < 4; ++mt)
        for (int r = 0; r < 4; ++r) {           // verified C/D layout: row=(l>>4)*4+r
            b1f[(mt*64 + lane)*4 + r] = b1[16*mt + g*4 + r];
            b2f[(mt*64 + lane)*4 + r] = b2[16*mt + g*4 + r];
        }
}

// block = 1 wave, min 3 waves/EU: per-wave reg budget ~168 >= our ~152 live
// (88 arch VGPR + ~64 MFMA-acc AGPRs, unified file) -> no spill (r7 spilled
// because the (64,4) budget of 128 was BELOW the live set). 3 waves/SIMD
// needs grid >= 12 blocks/CU -> grid 4096. LDS 9.2KB*12 = 111KB ok.
__global__ __launch_bounds__(64, 3) void node_warp_kernel(
    const float* __restrict__ ev, const char* __restrict__ ws,
    const float* __restrict__ b3g,
    float* __restrict__ out, int n, int* __restrict__ counter)
{
    // wave-private LDS (1 wave/block -> no barriers; LDS in-order per wave)
    __shared__ __align__(128) ushort Hs[64 * 64];   // 8KB [e][h] bf16, swz, H1->H2 reuse
    __shared__ __align__(128) float  Ks[64 * 4];    // 1KB per-event k-vector

    const int lane = threadIdx.x;
    const int g = lane >> 4, m = lane & 15;
    const bool g0 = (g == 0);

    const short8* W1f = (const short8*)(ws + WS_W1F);
    const short8* W2f = (const short8*)(ws + WS_W2F);
    const short8* W3f = (const short8*)(ws + WS_W3F);
    const f32x4*  b1f = (const f32x4*)(ws + WS_B1F);
    const f32x4*  b2f = (const f32x4*)(ws + WS_B2F);
    short8 W1r[4], W2r[2][4], W3r[2];
    f32x4  b1r[4], b2r[4];
#pragma unroll
    for (int mt = 0; mt < 4; ++mt) {
        W1r[mt] = W1f[mt*64 + lane];
        W2r[0][mt] = W2f[(0*4 + mt)*64 + lane];
        W2r[1][mt] = W2f[(1*4 + mt)*64 + lane];
        b1r[mt] = b1f[mt*64 + lane];
        b2r[mt] = b2f[mt*64 + lane];
    }
    W3r[0] = W3f[0*64 + lane];
    W3r[1] = W3f[1*64 + lane];
    const float b30 = b3g[0], b31 = b3g[1], b32 = b3g[2];
    const f32x4 zero4 = {0.f, 0.f, 0.f, 0.f};

    // per-lane LDS base pointers (swizzle pre-folded)
    // addr(e=16nt+m, off) = 2048*nt + 128*m + (off ^ ((m&7)<<4)),  off < 128
    char* HsB = (char*)Hs;
    const uint hswz = (uint)((m & 7) << 4);
    char* hwp[4];
#pragma unroll
    for (int mt = 0; mt < 4; ++mt)
        hwp[mt] = HsB + 128*m + ((uint)(32*mt + 8*g) ^ hswz);
    char* hrp[2];
#pragma unroll
    for (int kt = 0; kt < 2; ++kt)
        hrp[kt] = HsB + 128*m + ((uint)(16*g + 64*kt) ^ hswz);
    char* kwp = (char*)Ks + m * 16;
    const char* krp = (const char*)Ks + lane * 16;
    int xaddr[4];
#pragma unroll
    for (int nt = 0; nt < 4; ++nt) xaddr[nt] = (16*nt + m) * 4;  // bpermute bytes

    // one MLP field evaluation for the whole wave's 64 events
    auto stage_eval = [&](float x0, float x1, float x2, float ts,
                          float& r0, float& r1, float& r2) {
        uint px01 = cvt_pk_bf16(x0, x1);
        uint px23 = cvt_pk_bf16(x2, ts);
#pragma unroll
        for (int nt = 0; nt < 4; ++nt) {
            // ---- L1 B-frag: only k<4 nonzero -> 2 bpermutes, no LDS array ----
            uint b01 = (uint)__builtin_amdgcn_ds_bpermute(xaddr[nt], (int)px01);
            uint b23 = (uint)__builtin_amdgcn_ds_bpermute(xaddr[nt], (int)px23);
            uintx4 bxw = { g0 ? b01 : 0u, g0 ? b23 : 0u, 0u, 0u };
            short8 bx = __builtin_bit_cast(short8, bxw);

            // ---- L1: D1[h][e] = W1aug @ X^T + b1 (bias via C) ----
            f32x4 a0 = __builtin_amdgcn_mfma_f32_16x16x32_bf16(W1r[0], bx, b1r[0], 0, 0, 0);
            f32x4 a1 = __builtin_amdgcn_mfma_f32_16x16x32_bf16(W1r[1], bx, b1r[1], 0, 0, 0);
            f32x4 a2 = __builtin_amdgcn_mfma_f32_16x16x32_bf16(W1r[2], bx, b1r[2], 0, 0, 0);
            f32x4 a3 = __builtin_amdgcn_mfma_f32_16x16x32_bf16(W1r[3], bx, b1r[3], 0, 0, 0);

            // relu -> packed bf16 -> Hs
            {
                uint p0 = cvt_pk_bf16(fmaxf(a0[0],0.f), fmaxf(a0[1],0.f));
                uint p1 = cvt_pk_bf16(fmaxf(a0[2],0.f), fmaxf(a0[3],0.f));
                *(uint2*)(hwp[0] + 2048*nt) = make_uint2(p0, p1);
                p0 = cvt_pk_bf16(fmaxf(a1[0],0.f), fmaxf(a1[1],0.f));
                p1 = cvt_pk_bf16(fmaxf(a1[2],0.f), fmaxf(a1[3],0.f));
                *(uint2*)(hwp[1] + 2048*nt) = make_uint2(p0, p1);
                p0 = cvt_pk_bf16(fmaxf(a2[0],0.f), fmaxf(a2[1],0.f));
                p1 = cvt_pk_bf16(fmaxf(a2[2],0.f), fmaxf(a2[3],0.f));
                *(uint2*)(hwp[2] + 2048*nt) = make_uint2(p0, p1);
                p0 = cvt_pk_bf16(fmaxf(a3[0],0.f), fmaxf(a3[1],0.f));
                p1 = cvt_pk_bf16(fmaxf(a3[2],0.f), fmaxf(a3[3],0.f));
                *(uint2*)(hwp[3] + 2048*nt) = make_uint2(p0, p1);
            }

            // ---- L2: D2 = W2 @ H1^T + b2 ----
            short8 bh0 = *(const short8*)(hrp[0] + 2048*nt);
            short8 bh1 = *(const short8*)(hrp[1] + 2048*nt);
            f32x4 c0 = __builtin_amdgcn_mfma_f32_16x16x32_bf16(W2r[0][0], bh0, b2r[0], 0, 0, 0);
            f32x4 c1 = __builtin_amdgcn_mfma_f32_16x16x32_bf16(W2r[0][1], bh0, b2r[1], 0, 0, 0);
            f32x4 c2 = __builtin_amdgcn_mfma_f32_16x16x32_bf16(W2r[0][2], bh0, b2r[2], 0, 0, 0);
            f32x4 c3 = __builtin_amdgcn_mfma_f32_16x16x32_bf16(W2r[0][3], bh0, b2r[3], 0, 0, 0);
            c0 = __builtin_amdgcn_mfma_f32_16x16x32_bf16(W2r[1][0], bh1, c0, 0, 0, 0);
            c1 = __builtin_amdgcn_mfma_f32_16x16x32_bf16(W2r[1][1], bh1, c1, 0, 0, 0);
            c2 = __builtin_amdgcn_mfma_f32_16x16x32_bf16(W2r[1][2], bh1, c2, 0, 0, 0);
            c3 = __builtin_amdgcn_mfma_f32_16x16x32_bf16(W2r[1][3], bh1, c3, 0, 0, 0);

            // relu -> packed bf16 -> Hs (overwrite; per-wave LDS is in-order)
            {
                uint p0 = cvt_pk_bf16(fmaxf(c0[0],0.f), fmaxf(c0[1],0.f));
                uint p1 = cvt_pk_bf16(fmaxf(c0[2],0.f), fmaxf(c0[3],0.f));
                *(uint2*)(hwp[0] + 2048*nt) = make_uint2(p0, p1);
                p0 = cvt_pk_bf16(fmaxf(c1[0],0.f), fmaxf(c1[1],0.f));
                p1 = cvt_pk_bf16(fmaxf(c1[2],0.f), fmaxf(c1[3],0.f));
                *(uint2*)(hwp[1] + 2048*nt) = make_uint2(p0, p1);
                p0 = cvt_pk_bf16(fmaxf(c2[0],0.f), fmaxf(c2[1],0.f));
                p1 = cvt_pk_bf16(fmaxf(c2[2],0.f), fmaxf(c2[3],0.f));
                *(uint2*)(hwp[2] + 2048*nt) = make_uint2(p0, p1);
                p0 = cvt_pk_bf16(fmaxf(c3[0],0.f), fmaxf(c3[1],0.f));
                p1 = cvt_pk_bf16(fmaxf(c3[2],0.f), fmaxf(c3[3],0.f));
                *(uint2*)(hwp[3] + 2048*nt) = make_uint2(p0, p1);
            }

            // ---- L3: D3[r][e] = W3 @ H2^T (rows 0..2 valid) ----
            short8 d0 = *(const short8*)(hrp[0] + 2048*nt);
            short8 d1 = *(const short8*)(hrp[1] + 2048*nt);
            f32x4 k3 = __builtin_amdgcn_mfma_f32_16x16x32_bf16(W3r[0], d0, zero4, 0, 0, 0);
            k3 = __builtin_amdgcn_mfma_f32_16x16x32_bf16(W3r[1], d1, k3, 0, 0, 0);
            if (g0) *(f32x4*)(kwp + 256*nt) = k3;   // D rows 0..3 live in lane-group 0
        }
        f32x4 kv = *(const f32x4*)krp;
        r0 = kv[0] + b30; r1 = kv[1] + b31; r2 = kv[2] + b32;
    };

    // DOPRI5 tableau
    constexpr float a21 = 1.f/5.f;
    constexpr float a31 = 3.f/40.f,  a32c = 9.f/40.f;
    constexpr float a41 = 44.f/45.f, a42 = -56.f/15.f, a43 = 32.f/9.f;
    constexpr float a51 = 19372.f/6561.f, a52 = -25360.f/2187.f,
                    a53 = 64448.f/6561.f, a54 = -212.f/729.f;
    constexpr float a61 = 9017.f/3168.f,  a62 = -355.f/33.f,
                    a63 = 46732.f/5247.f, a64 = 49.f/176.f, a65 = -5103.f/18656.f;
    constexpr float a71 = 35.f/384.f, a73 = 500.f/1113.f, a74 = 125.f/192.f,
                    a75 = -2187.f/6784.f, a76 = 11.f/84.f;
    constexpr float e1 = (float)(35.0/384.0   - 5179.0/57600.0);
    constexpr float e3 = (float)(500.0/1113.0 - 7571.0/16695.0);
    constexpr float e4 = (float)(125.0/192.0  - 393.0/640.0);
    constexpr float e5 = (float)(-2187.0/6784.0 + 92097.0/339200.0);
    constexpr float e6 = (float)(11.0/84.0    - 187.0/2100.0);
    constexpr float e7 = (float)(-1.0/40.0);

    bool active = false, drained = false;
    int  idx = -1, iters = 0;
    float t = 0.f, dt = 0.05f, y0 = 0.f, y1 = 0.f, y2 = 0.f, pol = 0.f;
    float k00=0,k01=0,k02=0, k10=0,k11=0,k12=0, k20=0,k21=0,k22=0,
          k30=0,k31=0,k32=0, k40=0,k41=0,k42=0, k50=0,k51=0,k52=0,
          k60=0,k61=0,k62=0;

    for (;;) {
        if (!active && !drained) {
            int i = atomicAdd(counter, 1);
            if (i < n) {
                idx = i;
                float4 e4v = reinterpret_cast<const float4*>(ev)[i];
                y0 = e4v.x; y1 = e4v.y; y2 = e4v.z; pol = e4v.w;
                t = 0.f; dt = 0.05f; iters = 0;
                active = true;
            } else drained = true;
        }
        if (__all(!active)) break;

        float dt_e = fminf(dt, 1.0f - t);
        float y50 = y0, y51 = y1, y52 = y2;

        // stage evals are UNPREDICATED: MFMA needs all 64 lanes.
#pragma unroll 1
        for (int s = 0; s < 7; ++s) {
            float cs = 0.0f, yi0 = y0, yi1 = y1, yi2 = y2;
            switch (s) {
            case 0: break;
            case 1: cs = 0.2f;
                yi0 = fmaf(dt_e, a21*k00, y0);
                yi1 = fmaf(dt_e, a21*k01, y1);
                yi2 = fmaf(dt_e, a21*k02, y2);
                break;
            case 2: cs = 0.3f;
                yi0 = fmaf(dt_e, fmaf(a32c,k10, a31*k00), y0);
                yi1 = fmaf(dt_e, fmaf(a32c,k11, a31*k01), y1);
                yi2 = fmaf(dt_e, fmaf(a32c,k12, a31*k02), y2);
                break;
            case 3: cs = 0.8f;
                yi0 = fmaf(dt_e, fmaf(a43,k20, fmaf(a42,k10, a41*k00)), y0);
                yi1 = fmaf(dt_e, fmaf(a43,k21, fmaf(a42,k11, a41*k01)), y1);
                yi2 = fmaf(dt_e, fmaf(a43,k22, fmaf(a42,k12, a41*k02)), y2);
                break;
            case 4: cs = 8.f/9.f;
                yi0 = fmaf(dt_e, fmaf(a54,k30, fmaf(a53,k20, fmaf(a52,k10, a51*k00))), y0);
                yi1 = fmaf(dt_e, fmaf(a54,k31, fmaf(a53,k21, fmaf(a52,k11, a51*k01))), y1);
                yi2 = fmaf(dt_e, fmaf(a54,k32, fmaf(a53,k22, fmaf(a52,k12, a51*k02))), y2);
                break;
            case 5: cs = 1.0f;
                yi0 = fmaf(dt_e, fmaf(a65,k40, fmaf(a64,k30, fmaf(a63,k20, fmaf(a62,k10, a61*k00)))), y0);
                yi1 = fmaf(dt_e, fmaf(a65,k41, fmaf(a64,k31, fmaf(a63,k21, fmaf(a62,k11, a61*k01)))), y1);
                yi2 = fmaf(dt_e, fmaf(a65,k42, fmaf(a64,k32, fmaf(a63,k22, fmaf(a62,k12, a61*k02)))), y2);
                break;
            case 6: cs = 1.0f;
                yi0 = fmaf(dt_e, fmaf(a76,k50, fmaf(a75,k40, fmaf(a74,k30, fmaf(a73,k20, a71*k00)))), y0);
                yi1 = fmaf(dt_e, fmaf(a76,k51, fmaf(a75,k41, fmaf(a74,k31, fmaf(a73,k21, a71*k01)))), y1);
                yi2 = fmaf(dt_e, fmaf(a76,k52, fmaf(a75,k42, fmaf(a74,k32, fmaf(a73,k22, a71*k02)))), y2);
                y50 = yi0; y51 = yi1; y52 = yi2;   // FSAL: y5 == stage-7 input
                break;
            }
            float ts = fmaf(cs, dt_e, t);
            float r0, r1, r2;
            stage_eval(yi0, yi1, yi2, ts, r0, r1, r2);
            switch (s) {
            case 0: k00=r0; k01=r1; k02=r2; break;
            case 1: k10=r0; k11=r1; k12=r2; break;
            case 2: k20=r0; k21=r1; k22=r2; break;
            case 3: k30=r0; k31=r1; k32=r2; break;
            case 4: k40=r0; k41=r1; k42=r2; break;
            case 5: k50=r0; k51=r1; k52=r2; break;
            case 6: k60=r0; k61=r1; k62=r2; break;
            }
        }

        if (active) {
            float er0 = dt_e * fmaf(e7,k60, fmaf(e6,k50, fmaf(e5,k40, fmaf(e4,k30, fmaf(e3,k20, e1*k00)))));
            float er1 = dt_e * fmaf(e7,k61, fmaf(e6,k51, fmaf(e5,k41, fmaf(e4,k31, fmaf(e3,k21, e1*k01)))));
            float er2 = dt_e * fmaf(e7,k62, fmaf(e6,k52, fmaf(e5,k42, fmaf(e4,k32, fmaf(e3,k22, e1*k02)))));
            float s0 = fmaf(RTOL_K, fmaxf(fabsf(y0), fabsf(y50)), ATOL_K);
            float s1 = fmaf(RTOL_K, fmaxf(fabsf(y1), fabsf(y51)), ATOL_K);
            float s2 = fmaf(RTOL_K, fmaxf(fabsf(y2), fabsf(y52)), ATOL_K);
            float q0 = er0/s0, q1 = er1/s1, q2 = er2/s2;
            float en = sqrtf((q0*q0 + q1*q1 + q2*q2) * (1.0f/3.0f));
            en = fmaxf(en, 1e-10f);
            if (en <= 1.0f) { t += dt_e; y0 = y50; y1 = y51; y2 = y52; }
            float fac = fminf(fmaxf(0.9f * exp2f(-0.2f * log2f(en)), 0.2f), 10.0f);
            dt = dt_e * fac;
            ++iters;
            if (t >= 1.0f - 1e-9f || iters >= 64) {
                reinterpret_cast<float4*>(out)[idx] = make_float4(y0, y1, y2, pol);
                active = false;
            }
        }
    }
}

extern "C" void kernel_launch(void* const* d_in, const int* in_sizes, int n_in,
                              void* d_out, int out_size, void* d_ws, size_t ws_size,
                              hipStream_t stream)
{
    const float* events = (const float*)d_in[0];
    const float* W1 = (const float*)d_in[1];
    const float* b1 = (const float*)d_in[2];
    const float* W2 = (const float*)d_in[3];
    const float* b2 = (const float*)d_in[4];
    const float* W3 = (const float*)d_in[5];
    const float* b3 = (const float*)d_in[6];
    float* out = (float*)d_out;

    char* ws = (char*)d_ws;
    int* counter = (int*)(ws + WS_CNT);
    int n = in_sizes[0] / 4;

    hipMemsetAsync(counter, 0, sizeof(int), stream);
    hipLaunchKernelGGL(build_frags, dim3(1), dim3(64), 0, stream,
                       W1, b1, W2, b2, W3, b3, ws);

    // persistent 1-wave blocks: grid 4096 feeds 12+ blocks/CU; launch_bounds
    // (64,3) gives a ~168-reg budget >= live set -> 3 waves/SIMD, no spill.
    const int grid = 4096;
    hipLaunchKernelGGL(node_warp_kernel, dim3(grid), dim3(64), 0, stream,
                       events, ws, b3, out, n, counter);
}

// Round 13
// 861.019 us; speedup vs baseline: 1.9532x; 1.7716x over previous
//
#include <hip/hip_runtime.h>

typedef __attribute__((ext_vector_type(8))) short short8;
typedef __attribute__((ext_vector_type(4))) float f32x4;
typedef __attribute__((ext_vector_type(4))) uint  uintx4;

// Tolerance ladder: r3 showed 1e-5 -> 3e-4 halved steps with absmax FLAT at
// 0.0625 (error dominated by bf16-field systematic, not truncation). 1.5e-3
// adds <~0.08 truncation worst-case vs threshold 0.254. dt0=0.1 trims ramp.
#define RTOL_K 1.5e-3f
#define ATOL_K 1.5e-4f
#define DT0    0.1f

__device__ __forceinline__ ushort f2bf(float f) {
    union { float f; uint u; } v; v.f = f;
    uint r = v.u + 0x7fffu + ((v.u >> 16) & 1u);   // RNE
    return (ushort)(r >> 16);
}

// packed f32->bf16 (RNE), D.lo = cvt(a), D.hi = cvt(b)
__device__ __forceinline__ uint cvt_pk_bf16(float a, float b) {
    uint r;
    asm("v_cvt_pk_bf16_f32 %0, %1, %2" : "=v"(r) : "v"(a), "v"(b));
    return r;
}

// ws layout (bytes): W1f 0K | W2f 4K | W3f 12K | b1f 14K | b2f 18K | counter 22K
#define WS_W1F 0
#define WS_W2F 4096
#define WS_W3F 12288
#define WS_B1F 14336
#define WS_B2F 18432
#define WS_CNT 22528

// Assumed A/B fragment k-map: k=(lane>>4)*8+j, m/n=lane&15 — used consistently
// on build and dynamic packing so any k-permutation cancels in the MFMA sum.
__global__ __launch_bounds__(64) void build_frags(
    const float* __restrict__ W1, const float* __restrict__ b1,
    const float* __restrict__ W2, const float* __restrict__ b2,
    const float* __restrict__ W3, const float* __restrict__ b3,
    char* __restrict__ ws)
{
    int lane = threadIdx.x;
    int m = lane & 15, g = lane >> 4;
    ushort* w1f = (ushort*)(ws + WS_W1F);
    ushort* w2f = (ushort*)(ws + WS_W2F);
    ushort* w3f = (ushort*)(ws + WS_W3F);
    float*  b1f = (float*)(ws + WS_B1F);
    float*  b2f = (float*)(ws + WS_B2F);
    for (int mt = 0; mt < 4; ++mt)
        for (int j = 0; j < 8; ++j) {
            int k = g * 8 + j;
            w1f[(mt*64 + lane)*8 + j] = (k < 4) ? f2bf(W1[(16*mt + m)*4 + k]) : (ushort)0;
        }
    for (int kt = 0; kt < 2; ++kt)
        for (int mt = 0; mt < 4; ++mt)
            for (int j = 0; j < 8; ++j) {
                int k = 32*kt + g*8 + j;
                w2f[((kt*4 + mt)*64 + lane)*8 + j] = f2bf(W2[(16*mt + m)*64 + k]);
            }
    for (int kt = 0; kt < 2; ++kt)
        for (int j = 0; j < 8; ++j) {
            int k = 32*kt + g*8 + j;
            w3f[(kt*64 + lane)*8 + j] = (m < 3) ? f2bf(W3[m*64 + k]) : (ushort)0;
        }
    for (int mt = 0; mt < 4; ++mt)
        for (int r = 0; r < 4; ++r) {           // verified C/D layout: row=(l>>4)*4+r
            b1f[(mt*64 + lane)*4 + r] = b1[16*mt + g*4 + r];
            b2f[(mt*64 + lane)*4 + r] = b2[16*mt + g*4 + r];
        }
}

// block = 1 wave, min 3 waves/EU (r12: 33% occupancy, no spill). NOTE r12
// lesson: the LDS pipe is the saturated shared resource — occupancy beyond
// 3 waves/SIMD buys nothing; this round cuts total work instead.
__global__ __launch_bounds__(64, 3) void node_warp_kernel(
    const float* __restrict__ ev, const char* __restrict__ ws,
    const float* __restrict__ b3g,
    float* __restrict__ out, int n, int* __restrict__ counter)
{
    // wave-private LDS (1 wave/block -> no barriers; LDS in-order per wave)
    __shared__ __align__(128) ushort Hs[64 * 64];   // 8KB [e][h] bf16, swz, H1->H2 reuse
    __shared__ __align__(128) float  Ks[64 * 4];    // 1KB per-event k-vector

    const int lane = threadIdx.x;
    const int g = lane >> 4, m = lane & 15;
    const bool g0 = (g == 0);

    const short8* W1f = (const short8*)(ws + WS_W1F);
    const short8* W2f = (const short8*)(ws + WS_W2F);
    const short8* W3f = (const short8*)(ws + WS_W3F);
    const f32x4*  b1f = (const f32x4*)(ws + WS_B1F);
    const f32x4*  b2f = (const f32x4*)(ws + WS_B2F);
    short8 W1r[4], W2r[2][4], W3r[2];
    f32x4  b1r[4], b2r[4];
#pragma unroll
    for (int mt = 0; mt < 4; ++mt) {
        W1r[mt] = W1f[mt*64 + lane];
        W2r[0][mt] = W2f[(0*4 + mt)*64 + lane];
        W2r[1][mt] = W2f[(1*4 + mt)*64 + lane];
        b1r[mt] = b1f[mt*64 + lane];
        b2r[mt] = b2f[mt*64 + lane];
    }
    W3r[0] = W3f[0*64 + lane];
    W3r[1] = W3f[1*64 + lane];
    const float b30 = b3g[0], b31 = b3g[1], b32 = b3g[2];
    const f32x4 zero4 = {0.f, 0.f, 0.f, 0.f};

    // per-lane LDS base pointers (swizzle pre-folded)
    // addr(e=16nt+m, off) = 2048*nt + 128*m + (off ^ ((m&7)<<4)),  off < 128
    char* HsB = (char*)Hs;
    const uint hswz = (uint)((m & 7) << 4);
    char* hwp[4];
#pragma unroll
    for (int mt = 0; mt < 4; ++mt)
        hwp[mt] = HsB + 128*m + ((uint)(32*mt + 8*g) ^ hswz);
    char* hrp[2];
#pragma unroll
    for (int kt = 0; kt < 2; ++kt)
        hrp[kt] = HsB + 128*m + ((uint)(16*g + 64*kt) ^ hswz);
    char* kwp = (char*)Ks + m * 16;
    const char* krp = (const char*)Ks + lane * 16;
    int xaddr[4];
#pragma unroll
    for (int nt = 0; nt < 4; ++nt) xaddr[nt] = (16*nt + m) * 4;  // bpermute bytes

    // one MLP field evaluation for the whole wave's 64 events
    auto stage_eval = [&](float x0, float x1, float x2, float ts,
                          float& r0, float& r1, float& r2) {
        uint px01 = cvt_pk_bf16(x0, x1);
        uint px23 = cvt_pk_bf16(x2, ts);
#pragma unroll
        for (int nt = 0; nt < 4; ++nt) {
            // ---- L1 B-frag: only k<4 nonzero -> 2 bpermutes, no LDS array ----
            uint b01 = (uint)__builtin_amdgcn_ds_bpermute(xaddr[nt], (int)px01);
            uint b23 = (uint)__builtin_amdgcn_ds_bpermute(xaddr[nt], (int)px23);
            uintx4 bxw = { g0 ? b01 : 0u, g0 ? b23 : 0u, 0u, 0u };
            short8 bx = __builtin_bit_cast(short8, bxw);

            // ---- L1: D1[h][e] = W1aug @ X^T + b1 (bias via C) ----
            f32x4 a0 = __builtin_amdgcn_mfma_f32_16x16x32_bf16(W1r[0], bx, b1r[0], 0, 0, 0);
            f32x4 a1 = __builtin_amdgcn_mfma_f32_16x16x32_bf16(W1r[1], bx, b1r[1], 0, 0, 0);
            f32x4 a2 = __builtin_amdgcn_mfma_f32_16x16x32_bf16(W1r[2], bx, b1r[2], 0, 0, 0);
            f32x4 a3 = __builtin_amdgcn_mfma_f32_16x16x32_bf16(W1r[3], bx, b1r[3], 0, 0, 0);

            // relu -> packed bf16 -> Hs
            {
                uint p0 = cvt_pk_bf16(fmaxf(a0[0],0.f), fmaxf(a0[1],0.f));
                uint p1 = cvt_pk_bf16(fmaxf(a0[2],0.f), fmaxf(a0[3],0.f));
                *(uint2*)(hwp[0] + 2048*nt) = make_uint2(p0, p1);
                p0 = cvt_pk_bf16(fmaxf(a1[0],0.f), fmaxf(a1[1],0.f));
                p1 = cvt_pk_bf16(fmaxf(a1[2],0.f), fmaxf(a1[3],0.f));
                *(uint2*)(hwp[1] + 2048*nt) = make_uint2(p0, p1);
                p0 = cvt_pk_bf16(fmaxf(a2[0],0.f), fmaxf(a2[1],0.f));
                p1 = cvt_pk_bf16(fmaxf(a2[2],0.f), fmaxf(a2[3],0.f));
                *(uint2*)(hwp[2] + 2048*nt) = make_uint2(p0, p1);
                p0 = cvt_pk_bf16(fmaxf(a3[0],0.f), fmaxf(a3[1],0.f));
                p1 = cvt_pk_bf16(fmaxf(a3[2],0.f), fmaxf(a3[3],0.f));
                *(uint2*)(hwp[3] + 2048*nt) = make_uint2(p0, p1);
            }

            // ---- L2: D2 = W2 @ H1^T + b2 ----
            short8 bh0 = *(const short8*)(hrp[0] + 2048*nt);
            short8 bh1 = *(const short8*)(hrp[1] + 2048*nt);
            f32x4 c0 = __builtin_amdgcn_mfma_f32_16x16x32_bf16(W2r[0][0], bh0, b2r[0], 0, 0, 0);
            f32x4 c1 = __builtin_amdgcn_mfma_f32_16x16x32_bf16(W2r[0][1], bh0, b2r[1], 0, 0, 0);
            f32x4 c2 = __builtin_amdgcn_mfma_f32_16x16x32_bf16(W2r[0][2], bh0, b2r[2], 0, 0, 0);
            f32x4 c3 = __builtin_amdgcn_mfma_f32_16x16x32_bf16(W2r[0][3], bh0, b2r[3], 0, 0, 0);
            c0 = __builtin_amdgcn_mfma_f32_16x16x32_bf16(W2r[1][0], bh1, c0, 0, 0, 0);
            c1 = __builtin_amdgcn_mfma_f32_16x16x32_bf16(W2r[1][1], bh1, c1, 0, 0, 0);
            c2 = __builtin_amdgcn_mfma_f32_16x16x32_bf16(W2r[1][2], bh1, c2, 0, 0, 0);
            c3 = __builtin_amdgcn_mfma_f32_16x16x32_bf16(W2r[1][3], bh1, c3, 0, 0, 0);

            // relu -> packed bf16 -> Hs (overwrite; per-wave LDS is in-order)
            {
                uint p0 = cvt_pk_bf16(fmaxf(c0[0],0.f), fmaxf(c0[1],0.f));
                uint p1 = cvt_pk_bf16(fmaxf(c0[2],0.f), fmaxf(c0[3],0.f));
                *(uint2*)(hwp[0] + 2048*nt) = make_uint2(p0, p1);
                p0 = cvt_pk_bf16(fmaxf(c1[0],0.f), fmaxf(c1[1],0.f));
                p1 = cvt_pk_bf16(fmaxf(c1[2],0.f), fmaxf(c1[3],0.f));
                *(uint2*)(hwp[1] + 2048*nt) = make_uint2(p0, p1);
                p0 = cvt_pk_bf16(fmaxf(c2[0],0.f), fmaxf(c2[1],0.f));
                p1 = cvt_pk_bf16(fmaxf(c2[2],0.f), fmaxf(c2[3],0.f));
                *(uint2*)(hwp[2] + 2048*nt) = make_uint2(p0, p1);
                p0 = cvt_pk_bf16(fmaxf(c3[0],0.f), fmaxf(c3[1],0.f));
                p1 = cvt_pk_bf16(fmaxf(c3[2],0.f), fmaxf(c3[3],0.f));
                *(uint2*)(hwp[3] + 2048*nt) = make_uint2(p0, p1);
            }

            // ---- L3: D3[r][e] = W3 @ H2^T (rows 0..2 valid) ----
            short8 d0 = *(const short8*)(hrp[0] + 2048*nt);
            short8 d1 = *(const short8*)(hrp[1] + 2048*nt);
            f32x4 k3 = __builtin_amdgcn_mfma_f32_16x16x32_bf16(W3r[0], d0, zero4, 0, 0, 0);
            k3 = __builtin_amdgcn_mfma_f32_16x16x32_bf16(W3r[1], d1, k3, 0, 0, 0);
            if (g0) *(f32x4*)(kwp + 256*nt) = k3;   // D rows 0..3 live in lane-group 0
        }
        f32x4 kv = *(const f32x4*)krp;
        r0 = kv[0] + b30; r1 = kv[1] + b31; r2 = kv[2] + b32;
    };

    // DOPRI5 tableau
    constexpr float a21 = 1.f/5.f;
    constexpr float a31 = 3.f/40.f,  a32c = 9.f/40.f;
    constexpr float a41 = 44.f/45.f, a42 = -56.f/15.f, a43 = 32.f/9.f;
    constexpr float a51 = 19372.f/6561.f, a52 = -25360.f/2187.f,
                    a53 = 64448.f/6561.f, a54 = -212.f/729.f;
    constexpr float a61 = 9017.f/3168.f,  a62 = -355.f/33.f,
                    a63 = 46732.f/5247.f, a64 = 49.f/176.f, a65 = -5103.f/18656.f;
    constexpr float a71 = 35.f/384.f, a73 = 500.f/1113.f, a74 = 125.f/192.f,
                    a75 = -2187.f/6784.f, a76 = 11.f/84.f;
    constexpr float e1 = (float)(35.0/384.0   - 5179.0/57600.0);
    constexpr float e3 = (float)(500.0/1113.0 - 7571.0/16695.0);
    constexpr float e4 = (float)(125.0/192.0  - 393.0/640.0);
    constexpr float e5 = (float)(-2187.0/6784.0 + 92097.0/339200.0);
    constexpr float e6 = (float)(11.0/84.0    - 187.0/2100.0);
    constexpr float e7 = (float)(-1.0/40.0);

    bool active = false, drained = false;
    int  idx = -1, iters = 0;
    float t = 0.f, dt = DT0, y0 = 0.f, y1 = 0.f, y2 = 0.f, pol = 0.f;
    float k00=0,k01=0,k02=0, k10=0,k11=0,k12=0, k20=0,k21=0,k22=0,
          k30=0,k31=0,k32=0, k40=0,k41=0,k42=0, k50=0,k51=0,k52=0,
          k60=0,k61=0,k62=0;

    for (;;) {
        if (!active && !drained) {
            int i = atomicAdd(counter, 1);
            if (i < n) {
                idx = i;
                float4 e4v = reinterpret_cast<const float4*>(ev)[i];
                y0 = e4v.x; y1 = e4v.y; y2 = e4v.z; pol = e4v.w;
                t = 0.f; dt = DT0; iters = 0;
                active = true;
            } else drained = true;
        }
        if (__all(!active)) break;

        float dt_e = fminf(dt, 1.0f - t);
        float y50 = y0, y51 = y1, y52 = y2;

        // stage evals are UNPREDICATED: MFMA needs all 64 lanes.
#pragma unroll 1
        for (int s = 0; s < 7; ++s) {
            float cs = 0.0f, yi0 = y0, yi1 = y1, yi2 = y2;
            switch (s) {
            case 0: break;
            case 1: cs = 0.2f;
                yi0 = fmaf(dt_e, a21*k00, y0);
                yi1 = fmaf(dt_e, a21*k01, y1);
                yi2 = fmaf(dt_e, a21*k02, y2);
                break;
            case 2: cs = 0.3f;
                yi0 = fmaf(dt_e, fmaf(a32c,k10, a31*k00), y0);
                yi1 = fmaf(dt_e, fmaf(a32c,k11, a31*k01), y1);
                yi2 = fmaf(dt_e, fmaf(a32c,k12, a31*k02), y2);
                break;
            case 3: cs = 0.8f;
                yi0 = fmaf(dt_e, fmaf(a43,k20, fmaf(a42,k10, a41*k00)), y0);
                yi1 = fmaf(dt_e, fmaf(a43,k21, fmaf(a42,k11, a41*k01)), y1);
                yi2 = fmaf(dt_e, fmaf(a43,k22, fmaf(a42,k12, a41*k02)), y2);
                break;
            case 4: cs = 8.f/9.f;
                yi0 = fmaf(dt_e, fmaf(a54,k30, fmaf(a53,k20, fmaf(a52,k10, a51*k00))), y0);
                yi1 = fmaf(dt_e, fmaf(a54,k31, fmaf(a53,k21, fmaf(a52,k11, a51*k01))), y1);
                yi2 = fmaf(dt_e, fmaf(a54,k32, fmaf(a53,k22, fmaf(a52,k12, a51*k02))), y2);
                break;
            case 5: cs = 1.0f;
                yi0 = fmaf(dt_e, fmaf(a65,k40, fmaf(a64,k30, fmaf(a63,k20, fmaf(a62,k10, a61*k00)))), y0);
                yi1 = fmaf(dt_e, fmaf(a65,k41, fmaf(a64,k31, fmaf(a63,k21, fmaf(a62,k11, a61*k01)))), y1);
                yi2 = fmaf(dt_e, fmaf(a65,k42, fmaf(a64,k32, fmaf(a63,k22, fmaf(a62,k12, a61*k02)))), y2);
                break;
            case 6: cs = 1.0f;
                yi0 = fmaf(dt_e, fmaf(a76,k50, fmaf(a75,k40, fmaf(a74,k30, fmaf(a73,k20, a71*k00)))), y0);
                yi1 = fmaf(dt_e, fmaf(a76,k51, fmaf(a75,k41, fmaf(a74,k31, fmaf(a73,k21, a71*k01)))), y1);
                yi2 = fmaf(dt_e, fmaf(a76,k52, fmaf(a75,k42, fmaf(a74,k32, fmaf(a73,k22, a71*k02)))), y2);
                y50 = yi0; y51 = yi1; y52 = yi2;   // FSAL: y5 == stage-7 input
                break;
            }
            float ts = fmaf(cs, dt_e, t);
            float r0, r1, r2;
            stage_eval(yi0, yi1, yi2, ts, r0, r1, r2);
            switch (s) {
            case 0: k00=r0; k01=r1; k02=r2; break;
            case 1: k10=r0; k11=r1; k12=r2; break;
            case 2: k20=r0; k21=r1; k22=r2; break;
            case 3: k30=r0; k31=r1; k32=r2; break;
            case 4: k40=r0; k41=r1; k42=r2; break;
            case 5: k50=r0; k51=r1; k52=r2; break;
            case 6: k60=r0; k61=r1; k62=r2; break;
            }
        }

        if (active) {
            float er0 = dt_e * fmaf(e7,k60, fmaf(e6,k50, fmaf(e5,k40, fmaf(e4,k30, fmaf(e3,k20, e1*k00)))));
            float er1 = dt_e * fmaf(e7,k61, fmaf(e6,k51, fmaf(e5,k41, fmaf(e4,k31, fmaf(e3,k21, e1*k01)))));
            float er2 = dt_e * fmaf(e7,k62, fmaf(e6,k52, fmaf(e5,k42, fmaf(e4,k32, fmaf(e3,k22, e1*k02)))));
            float s0 = fmaf(RTOL_K, fmaxf(fabsf(y0), fabsf(y50)), ATOL_K);
            float s1 = fmaf(RTOL_K, fmaxf(fabsf(y1), fabsf(y51)), ATOL_K);
            float s2 = fmaf(RTOL_K, fmaxf(fabsf(y2), fabsf(y52)), ATOL_K);
            float q0 = er0/s0, q1 = er1/s1, q2 = er2/s2;
            float en = sqrtf((q0*q0 + q1*q1 + q2*q2) * (1.0f/3.0f));
            en = fmaxf(en, 1e-10f);
            if (en <= 1.0f) { t += dt_e; y0 = y50; y1 = y51; y2 = y52; }
            float fac = fminf(fmaxf(0.9f * exp2f(-0.2f * log2f(en)), 0.2f), 10.0f);
            dt = dt_e * fac;
            ++iters;
            if (t >= 1.0f - 1e-9f || iters >= 64) {
                reinterpret_cast<float4*>(out)[idx] = make_float4(y0, y1, y2, pol);
                active = false;
            }
        }
    }
}

extern "C" void kernel_launch(void* const* d_in, const int* in_sizes, int n_in,
                              void* d_out, int out_size, void* d_ws, size_t ws_size,
                              hipStream_t stream)
{
    const float* events = (const float*)d_in[0];
    const float* W1 = (const float*)d_in[1];
    const float* b1 = (const float*)d_in[2];
    const float* W2 = (const float*)d_in[3];
    const float* b2 = (const float*)d_in[4];
    const float* W3 = (const float*)d_in[5];
    const float* b3 = (const float*)d_in[6];
    float* out = (float*)d_out;

    char* ws = (char*)d_ws;
    int* counter = (int*)(ws + WS_CNT);
    int n = in_sizes[0] / 4;

    hipMemsetAsync(counter, 0, sizeof(int), stream);
    hipLaunchKernelGGL(build_frags, dim3(1), dim3(64), 0, stream,
                       W1, b1, W2, b2, W3, b3, ws);

    const int grid = 4096;
    hipLaunchKernelGGL(node_warp_kernel, dim3(grid), dim3(64), 0, stream,
                       events, ws, b3, out, n, counter);
}